// Round 7
// baseline (606.169 us; speedup 1.0000x reference)
//
#include <hip/hip_runtime.h>
#include <math.h>

// Problem constants
#define N_IMG 128
#define IC 8
#define IH 128
#define IW 128
#define OC 64
#define OH 126
#define OW 126
#define NG 16
#define CPG 4          // channels per group
#define PH 31
#define PW 31
#define GN_EPS 1e-5f

// Transpose conv_w [oc][ic][3][3] -> wt[g][ic][kh][kw][ch] so the main kernel
// can read each (ic,kh) slice of 12 floats with UNIFORM addresses (s_load into
// SGPRs; v_fma takes the weight as its one scalar operand). This removes the
// weight ds_read traffic that oversubscribed the LDS pipe 1.5x in R2-R6.
__global__ void prep_weights_kernel(const float* __restrict__ conv_w,
                                    float* __restrict__ wt) {
    int t = blockIdx.x * 256 + threadIdx.x;
    if (t < NG * IC * 9 * CPG) {
        int ch = t & 3;
        int q = t >> 2;            // (g*IC + ic)*9 + r
        int r = q % 9;             // kh*3 + kw
        int ic = (q / 9) % IC;
        int g = q / (9 * IC);
        wt[t] = conv_w[(g * CPG + ch) * (IC * 9) + ic * 9 + r];
    }
}

// One block per (n, group). Single conv pass, conv8 tasks:
//  - 512 tasks/block: (ph 0..30 => 4 conv rows; ph=31 => stats-only rows
//    124,125) x 16 column-octets (col0 = 8k; k=15 covers the right-edge
//    stats cols 124,125 and 2 dead lanes).
//  - per (ic,kh): 2 float4 + 1 float2 input loads + 12 scalar weights feeding
//    96 FMAs. No LDS in the hot loop.
//  - GN stats per thread; pool via max-before-affine trick (slope sign known
//    before stats since rstd>0); pool extremes live in registers.
// Blocks swizzled so all 16 groups of image n land on XCD n%8 back-to-back.
__launch_bounds__(256, 4)
__global__ void fused_conv_gn_pool_kernel(const float* __restrict__ x,
                                          const float* __restrict__ wt,
                                          const float* __restrict__ conv_b,
                                          const float* __restrict__ gn_w,
                                          const float* __restrict__ gn_b,
                                          const float* __restrict__ scale,
                                          float* __restrict__ out) {
    // XCD swizzle: XCD(b) = b % 8 (round-robin dispatch).
    const int b = blockIdx.x;
    const int xcd = b & 7;
    const int slot = b >> 3;           // 0..255
    const int g = slot & 15;
    const int n = xcd + 8 * (slot >> 4);
    const int tid = threadIdx.x;

    __shared__ float red[8];
    __shared__ float stats[2];

    const float* __restrict__ wg = wt + g * (IC * 9 * CPG);   // uniform

    float bias[CPG], sgnf[CPG];
#pragma unroll
    for (int ch = 0; ch < CPG; ch++) {
        int c = g * CPG + ch;
        bias[ch] = conv_b[c];
        sgnf[ch] = (gn_w[c] * scale[c] >= 0.f) ? 1.f : -1.f;
    }

    const float* xb = x + (size_t)n * (IC * IH * IW);

    float s = 0.f, ss = 0.f;
    float pm[2][2][CPG];             // [task ci][half-octet][ch]
#pragma unroll
    for (int ci = 0; ci < 2; ci++)
#pragma unroll
        for (int hf = 0; hf < 2; hf++)
#pragma unroll
            for (int ch = 0; ch < CPG; ch++) pm[ci][hf][ch] = -INFINITY;

#pragma unroll 1
    for (int ci = 0; ci < 2; ci++) {
        const int id = tid + ci * 256;     // 0..511
        const int ph = id & 31;            // 0..31 (31 => stats-only rows)
        const int k = id >> 5;             // 0..15 column octet
        const int col0 = k * 8;
        const bool ktail = (k == 15);      // cols 120..127; valid <=125
        const int row0 = 4 * ph;           // ph=31 -> 124
        const int nrows = (ph == 31) ? 2 : 4;

#pragma unroll 1
        for (int r = 0; r < nrows; r++) {
            const int oh = row0 + r;
            float acc[8][CPG];
#pragma unroll
            for (int j = 0; j < 8; j++)
#pragma unroll
                for (int ch = 0; ch < CPG; ch++) acc[j][ch] = bias[ch];

#pragma unroll 1
            for (int ic = 0; ic < IC; ic++) {
                const float* xrowb = xb + ic * (IH * IW) + oh * IW + col0;
#pragma unroll
                for (int kh = 0; kh < 3; kh++) {
                    const float* xr = xrowb + kh * IW;
                    float4 a4 = *(const float4*)xr;        // cols col0..+3
                    float4 b4 = *(const float4*)(xr + 4);  // cols +4..+7
                    float v8 = 0.f, v9 = 0.f;
                    if (!ktail) {
                        float2 c2 = *(const float2*)(xr + 8);
                        v8 = c2.x; v9 = c2.y;
                    }
                    float v[10];
                    v[0] = a4.x; v[1] = a4.y; v[2] = a4.z; v[3] = a4.w;
                    v[4] = b4.x; v[5] = b4.y; v[6] = b4.z; v[7] = b4.w;
                    v[8] = v8;   v[9] = v9;
                    const float* wk = wg + (ic * 3 + kh) * 12;  // uniform -> s_load
#pragma unroll
                    for (int ch = 0; ch < CPG; ch++) {
                        float w0 = wk[0 + ch];
                        float w1 = wk[4 + ch];
                        float w2 = wk[8 + ch];
#pragma unroll
                        for (int j = 0; j < 8; j++)
                            acc[j][ch] = fmaf(v[j], w0,
                                         fmaf(v[j + 1], w1,
                                         fmaf(v[j + 2], w2, acc[j][ch])));
                    }
                }
            }

            // Stats (cols col0+j <= 125) + per-row pool fold
            const int jmax = ktail ? 6 : 8;
#pragma unroll
            for (int j = 0; j < 8; j++) {
                if (j < jmax) {
#pragma unroll
                    for (int ch = 0; ch < CPG; ch++) {
                        float v = acc[j][ch];
                        s += v;
                        ss = fmaf(v, v, ss);
                    }
                }
            }
            if (ph < 31) {
#pragma unroll
                for (int hf = 0; hf < 2; hf++)
#pragma unroll
                    for (int j = 0; j < 4; j++)
#pragma unroll
                        for (int ch = 0; ch < CPG; ch++)
                            pm[ci][hf][ch] = fmaxf(pm[ci][hf][ch],
                                                   acc[hf * 4 + j][ch] * sgnf[ch]);
            }
        }
    }

    // ---- Block reduction for GN stats ----
#pragma unroll
    for (int off = 32; off > 0; off >>= 1) {
        s  += __shfl_down(s, off, 64);
        ss += __shfl_down(ss, off, 64);
    }
    int wave = tid >> 6;
    if ((tid & 63) == 0) { red[wave] = s; red[4 + wave] = ss; }
    __syncthreads();
    if (tid == 0) {
        float S  = red[0] + red[1] + red[2] + red[3];
        float SS = red[4] + red[5] + red[6] + red[7];
        const float inv_count = 1.f / (float)(CPG * OH * OW);
        float mean = S * inv_count;
        float var = SS * inv_count - mean * mean;
        if (var < 0.f) var = 0.f;
        stats[0] = mean;
        stats[1] = rsqrtf(var + GN_EPS);
    }
    __syncthreads();
    const float mean = stats[0];
    const float rstd = stats[1];

    // Fused affine for the pooled extreme: out = a2*M + b2  (a2 >= 0)
    float a2[CPG], b2[CPG];
#pragma unroll
    for (int ch = 0; ch < CPG; ch++) {
        int c = g * CPG + ch;
        float gw = gn_w[c], sc = scale[c];
        a2[ch] = rstd * fabsf(gw * sc);
        b2[ch] = (gn_b[c] - mean * rstd * gw) * sc;
    }

    // ---- Write pooled, clamped output ----
#pragma unroll
    for (int ci = 0; ci < 2; ci++) {
        const int id = tid + ci * 256;
        const int ph = id & 31;
        const int k = id >> 5;
        if (ph < 31) {
#pragma unroll
            for (int hf = 0; hf < 2; hf++) {
                int pw = 2 * k + hf;
                if (pw < PW) {
#pragma unroll
                    for (int ch = 0; ch < CPG; ch++) {
                        int c = g * CPG + ch;
                        float v = fmaf(a2[ch], pm[ci][hf][ch], b2[ch]);
                        v = fminf(fmaxf(v, 0.f), 1.f);
                        out[(((size_t)n * OC + c) * PH + ph) * PW + pw] = v;
                    }
                }
            }
        }
    }
}

extern "C" void kernel_launch(void* const* d_in, const int* in_sizes, int n_in,
                              void* d_out, int out_size, void* d_ws, size_t ws_size,
                              hipStream_t stream) {
    const float* x      = (const float*)d_in[0];
    const float* conv_w = (const float*)d_in[1];
    const float* conv_b = (const float*)d_in[2];
    const float* gn_w   = (const float*)d_in[3];
    const float* gn_b   = (const float*)d_in[4];
    const float* scale  = (const float*)d_in[5];
    float* out = (float*)d_out;
    float* wt = (float*)d_ws;        // 16*288 floats = 18 KB scratch

    // Transpose weights for uniform (scalar) access in the main kernel.
    hipLaunchKernelGGL(prep_weights_kernel, dim3(18), dim3(256), 0, stream,
                       conv_w, wt);

    dim3 grid(N_IMG * NG);   // one block per (n, group), XCD-swizzled in-kernel
    dim3 block(256);
    hipLaunchKernelGGL(fused_conv_gn_pool_kernel, grid, block, 0, stream,
                       x, wt, conv_b, gn_w, gn_b, scale, out);
}